// Round 2
// baseline (438.477 us; speedup 1.0000x reference)
//
#include <hip/hip_runtime.h>
#include <stdint.h>

#define TPB   256
#define MTOP  50
#define EPSF  1e-8f

// Padded histogram indexing: 4096 bins stored as [256 groups][16+1 pad].
// Bin b lives at word (b>>4)*17 + (b&15). 17 is odd -> stride-17 scans are
// bank-conflict-free (17 invertible mod 32; 64 lanes alias exactly 2-way = free).
#define PIDX(b)   ((((b) >> 4) * 17) + ((b) & 15))
#define HWORDS    (256 * 17)          // 4352 words incl. pads
#define SWORDS    (16 * 17)           // padded segsum (256 entries + pads)

// monotonic float->uint key: larger float => larger key (handles negatives,
// needed because bce can be ~ -1e-8 from the log(1+eps) branch)
__device__ __forceinline__ uint32_t f2key(float f) {
    uint32_t b = __float_as_uint(f);
    return (b & 0x80000000u) ? ~b : (b | 0x80000000u);
}
__device__ __forceinline__ float key2f(uint32_t k) {
    uint32_t b = (k & 0x80000000u) ? (k ^ 0x80000000u) : ~k;
    return __uint_as_float(b);
}

struct SelShared {
    uint32_t hist[HWORDS];    // padded 4096-bin histogram
    uint32_t segsum[SWORDS];  // padded 256 segment sums
    uint32_t supsum[16];
    int rem;
    int bin;
};

// Rank-select over 4096 padded bins, scanning from the TOP bin downward.
// On entry S.rem = target rank (1-based from top). On exit S.bin = bin index,
// S.rem = residual rank within that bin.
__device__ void select4096(SelShared& S, int tid) {
    {
        uint32_t s = 0;
        #pragma unroll
        for (int j = 0; j < 16; ++j) s += S.hist[tid * 17 + j];       // stride-17: conflict-free
        S.segsum[(tid >> 4) * 17 + (tid & 15)] = s;
    }
    __syncthreads();
    if (tid < 16) {
        uint32_t s = 0;
        #pragma unroll
        for (int j = 0; j < 16; ++j) s += S.segsum[tid * 17 + j];     // conflict-free
        S.supsum[tid] = s;
    }
    __syncthreads();
    if (tid == 0) {
        int rem = S.rem;
        int sup = 15;
        for (; sup > 0; --sup) {
            int c = (int)S.supsum[sup];
            if (c >= rem) break;
            rem -= c;
        }
        int j = 15;
        for (; j > 0; --j) {
            int c = (int)S.segsum[sup * 17 + j];
            if (c >= rem) break;
            rem -= c;
        }
        const int seg = (sup << 4) + j;
        int m = 15;
        for (; m > 0; --m) {
            int c = (int)S.hist[seg * 17 + m];
            if (c >= rem) break;
            rem -= c;
        }
        S.rem = rem;
        S.bin = (seg << 4) + m;
    }
    __syncthreads();
}

// Rank-select over 256 padded bins (bin b at PIDX(b), groups 0..15).
__device__ void select256(SelShared& S, int tid) {
    if (tid < 16) {
        uint32_t s = 0;
        #pragma unroll
        for (int j = 0; j < 16; ++j) s += S.hist[tid * 17 + j];
        S.supsum[tid] = s;
    }
    __syncthreads();
    if (tid == 0) {
        int rem = S.rem;
        int sup = 15;
        for (; sup > 0; --sup) {
            int c = (int)S.supsum[sup];
            if (c >= rem) break;
            rem -= c;
        }
        int m = 15;
        for (; m > 0; --m) {
            int c = (int)S.hist[sup * 17 + m];
            if (c >= rem) break;
            rem -= c;
        }
        S.rem = rem;
        S.bin = (sup << 4) + m;
    }
    __syncthreads();
}

__global__ __launch_bounds__(TPB)
void bce_topk_kernel(const float* __restrict__ logits,
                     const float* __restrict__ targets,
                     float* __restrict__ out,
                     int Lr, float scale)
{
    extern __shared__ uint32_t smem[];
    uint32_t* keys = smem;                       // Lr words
    SelShared& S = *(SelShared*)(smem + ((Lr + 3) & ~3));
    __shared__ float    wred[4];
    __shared__ uint32_t wcnt[4];

    const int tid = threadIdx.x;
    const size_t rowbase = (size_t)blockIdx.x * (size_t)Lr;
    const float4* lg = (const float4*)(logits + rowbase);
    const float4* tg = (const float4*)(targets + rowbase);

    // zero histogram (incl. pads), init rank
    for (int i = tid; i < HWORDS; i += TPB) S.hist[i] = 0;
    if (tid == 0) S.rem = MTOP;

    // ---- Pass A: pure streaming — global float4 -> bce -> uint4 keys in LDS.
    // No atomics here so the compiler can software-pipeline the loads.
    const int nv = Lr >> 2;
    for (int i = tid; i < nv; i += TPB) {
        float4 x = lg[i];
        float4 t = tg[i];
        float xv[4] = {x.x, x.y, x.z, x.w};
        float tv[4] = {t.x, t.y, t.z, t.w};
        uint32_t kk[4];
        #pragma unroll
        for (int j = 0; j < 4; ++j) {
            float p = 1.0f / (1.0f + __expf(-xv[j]));
            float q = (tv[j] != 0.0f) ? p : (1.0f - p);
            kk[j] = f2key(-__logf(q + EPSF));
        }
        *(uint4*)(&keys[i << 2]) = make_uint4(kk[0], kk[1], kk[2], kk[3]);
    }
    // scalar tail (Lr % 4 != 0 safety; no-op for Lr=10000)
    for (int i = (nv << 2) + tid; i < Lr; i += TPB) {
        float p = 1.0f / (1.0f + __expf(-logits[rowbase + i]));
        float q = (targets[rowbase + i] != 0.0f) ? p : (1.0f - p);
        keys[i] = f2key(-__logf(q + EPSF));
    }
    __syncthreads();

    // ---- Pass B: histogram top-12 key bits from LDS (b128 key reads).
    for (int i = tid; i < nv; i += TPB) {
        uint4 kv = *(const uint4*)(&keys[i << 2]);
        atomicAdd(&S.hist[PIDX(kv.x >> 20)], 1u);
        atomicAdd(&S.hist[PIDX(kv.y >> 20)], 1u);
        atomicAdd(&S.hist[PIDX(kv.z >> 20)], 1u);
        atomicAdd(&S.hist[PIDX(kv.w >> 20)], 1u);
    }
    for (int i = (nv << 2) + tid; i < Lr; i += TPB)
        atomicAdd(&S.hist[PIDX(keys[i] >> 20)], 1u);
    __syncthreads();

    // ---- Select pass 1: top 12 bits
    select4096(S, tid);
    const uint32_t pref1 = (uint32_t)S.bin;

    // ---- Select pass 2: middle 12 bits among matching elements
    for (int i = tid; i < HWORDS; i += TPB) S.hist[i] = 0;
    __syncthreads();
    for (int i = tid; i < Lr; i += TPB) {
        uint32_t k = keys[i];
        if ((k >> 20) == pref1) atomicAdd(&S.hist[PIDX((k >> 8) & 0xFFFu)], 1u);
    }
    __syncthreads();
    select4096(S, tid);
    const uint32_t pref2 = (pref1 << 12) | (uint32_t)S.bin;

    // ---- Select pass 3: low 8 bits
    for (int i = tid; i < SWORDS; i += TPB) S.hist[i] = 0;   // 256 bins + pads
    __syncthreads();
    for (int i = tid; i < Lr; i += TPB) {
        uint32_t k = keys[i];
        if ((k >> 8) == pref2) atomicAdd(&S.hist[PIDX(k & 0xFFu)], 1u);
    }
    __syncthreads();
    select256(S, tid);
    const uint32_t K = (pref2 << 8) | (uint32_t)S.bin;

    // ---- Final: sum values strictly greater than K + tie correction.
    float sum = 0.0f;
    uint32_t cnt = 0;
    for (int i = tid; i < nv; i += TPB) {
        uint4 kv = *(const uint4*)(&keys[i << 2]);
        if (kv.x > K) { sum += key2f(kv.x); cnt++; }
        if (kv.y > K) { sum += key2f(kv.y); cnt++; }
        if (kv.z > K) { sum += key2f(kv.z); cnt++; }
        if (kv.w > K) { sum += key2f(kv.w); cnt++; }
    }
    for (int i = (nv << 2) + tid; i < Lr; i += TPB) {
        uint32_t k = keys[i];
        if (k > K) { sum += key2f(k); cnt++; }
    }
    #pragma unroll
    for (int off = 32; off > 0; off >>= 1) {
        sum += __shfl_down(sum, off);
        cnt += __shfl_down(cnt, off);
    }
    const int wid = tid >> 6;
    if ((tid & 63) == 0) { wred[wid] = sum; wcnt[wid] = cnt; }
    __syncthreads();
    if (tid == 0) {
        float s = wred[0] + wred[1] + wred[2] + wred[3];
        int   c = (int)(wcnt[0] + wcnt[1] + wcnt[2] + wcnt[3]);
        float tot = s + (float)(MTOP - c) * key2f(K);
        atomicAdd(out, tot * scale);
    }
}

extern "C" void kernel_launch(void* const* d_in, const int* in_sizes, int n_in,
                              void* d_out, int out_size, void* d_ws, size_t ws_size,
                              hipStream_t stream) {
    const float* logits  = (const float*)d_in[0];
    const float* targets = (const float*)d_in[1];
    float* out = (float*)d_out;

    const int Lr = 10000;                // row length
    const int B  = in_sizes[0] / Lr;     // 4096 rows
    const float scale = 1.0f / ((float)MTOP * (float)B);

    // dynamic LDS: keys (Lr words, rounded to uint4) + SelShared
    const size_t shbytes = (((Lr + 3) & ~3) + HWORDS + SWORDS + 16 + 2 + 8) * sizeof(uint32_t);

    hipMemsetAsync(out, 0, sizeof(float), stream);
    bce_topk_kernel<<<B, TPB, shbytes, stream>>>(logits, targets, out, Lr, scale);
}

// Round 3
// 345.147 us; speedup vs baseline: 1.2704x; 1.2704x over previous
//
#include <hip/hip_runtime.h>
#include <stdint.h>

#define TPB   256
#define MTOP  50
#define EPSF  1e-8f
#define NK    10              // uint4-groups per thread: covers nv = 10000/4 = 2500
#define HWORDS (256 * 17)     // 4096-bin hist, padded [256 groups][16+1]
#define SEGW   (16 * 17)      // padded 256 segment sums

// monotonic float->uint key (handles the tiny-negative bce from log(1+eps))
__device__ __forceinline__ uint32_t f2key(float f) {
    uint32_t b = __float_as_uint(f);
    return (b & 0x80000000u) ? ~b : (b | 0x80000000u);
}
__device__ __forceinline__ float key2f(uint32_t k) {
    uint32_t b = (k & 0x80000000u) ? (k ^ 0x80000000u) : ~k;
    return __uint_as_float(b);
}

struct Shared {
    uint32_t hist[HWORDS];
    uint32_t segsum[SEGW];
    int bin, rem;
    float    wred[4];
    uint32_t wcnt[4];
};

// Wave-parallel rank-pick over 16 values held by lanes 0..15 (lanes>=16 hold 0).
// Scanning from index 15 downward, find first idx where the running count
// reaches rem; update rem to the residual within that idx. All 64 lanes of
// the wave must execute this. ~15 shfl + 1 ballot instead of 16 dependent
// LDS reads.
__device__ __forceinline__ int pick16(uint32_t v, int lane, int& rem) {
    uint32_t sfx = v;                         // suffix sum: sfx[s] = sum_{u>=s} v[u]
    #pragma unroll
    for (int off = 1; off < 16; off <<= 1) {
        uint32_t t = __shfl_down(sfx, off);
        if (lane + off < 16) sfx += t;
    }
    bool p = (lane < 16) && ((int)sfx >= rem);
    unsigned long long m = __ballot(p);       // nonzero: sfx[0]=total >= rem
    int idx = 63 - __builtin_clzll(m);        // largest s with suffix >= rem
    uint32_t sfx_at = __shfl(sfx, idx);
    uint32_t v_at   = __shfl(v,   idx);
    rem -= (int)(sfx_at - v_at);              // subtract counts strictly above idx
    return idx;
}

// Rank-select over the padded 4096-bin hist. In: S.rem. Out: S.bin, S.rem.
__device__ void select4096(Shared& S, int tid) {
    uint32_t s = 0;
    #pragma unroll
    for (int j = 0; j < 16; ++j) s += S.hist[tid * 17 + j];   // stride-17: conflict-free
    S.segsum[(tid >> 4) * 17 + (tid & 15)] = s;
    __syncthreads();
    if (tid < 64) {                                           // wave 0 only
        const int lane = tid;
        int rem = S.rem;
        uint32_t sup = 0;
        if (lane < 16) {
            #pragma unroll
            for (int j = 0; j < 16; ++j) sup += S.segsum[lane * 17 + j];
        }
        const int s1 = pick16(sup, lane, rem);
        const uint32_t seg = (lane < 16) ? S.segsum[s1 * 17 + lane] : 0;
        const int s2 = pick16(seg, lane, rem);
        const int g = (s1 << 4) + s2;
        const uint32_t h = (lane < 16) ? S.hist[g * 17 + lane] : 0;
        const int s3 = pick16(h, lane, rem);
        if (lane == 0) { S.bin = (g << 4) + s3; S.rem = rem; }
    }
    __syncthreads();
}

// Rank-select over 256 padded bins (groups 0..15).
__device__ void select256(Shared& S, int tid) {
    if (tid < 64) {
        const int lane = tid;
        int rem = S.rem;
        uint32_t sup = 0;
        if (lane < 16) {
            #pragma unroll
            for (int j = 0; j < 16; ++j) sup += S.hist[lane * 17 + j];
        }
        const int s1 = pick16(sup, lane, rem);
        const uint32_t h = (lane < 16) ? S.hist[s1 * 17 + lane] : 0;
        const int s2 = pick16(h, lane, rem);
        if (lane == 0) { S.bin = (s1 << 4) + s2; S.rem = rem; }
    }
    __syncthreads();
}

__global__ __launch_bounds__(TPB, 4)
void bce_topk_kernel(const float* __restrict__ logits,
                     const float* __restrict__ targets,
                     float* __restrict__ out,
                     int Lr, float scale)
{
    __shared__ Shared S;
    const int tid = threadIdx.x;
    const size_t rowbase = (size_t)blockIdx.x * (size_t)Lr;
    const float4* lg = (const float4*)(logits + rowbase);
    const float4* tg = (const float4*)(targets + rowbase);
    const int nv = Lr >> 2;

    #pragma unroll
    for (int k = 0; k < 17; ++k) S.hist[tid + k * TPB] = 0;
    if (tid == 0) S.rem = MTOP;
    __syncthreads();

    // ---- Pass A (fused): stream global -> bce keys in REGISTERS + top-12-bit hist.
    // bce kept in log2 domain (monotonic); final scale multiplies by ln2.
    uint32_t kk[NK][4];
    #pragma unroll
    for (int k = 0; k < NK; ++k) {
        const int i = tid + k * TPB;
        const bool ok = (i < nv);
        const int ii = ok ? i : 0;
        const float4 x = lg[ii];
        const float4 t = tg[ii];
        const float xv[4] = {x.x, x.y, x.z, x.w};
        const float tv[4] = {t.x, t.y, t.z, t.w};
        #pragma unroll
        for (int j = 0; j < 4; ++j) {
            const float s = (tv[j] != 0.0f) ? xv[j] : -xv[j];
            const float e = __expf(-s);                         // e^-s
            const float q = __builtin_amdgcn_rcpf(1.0f + e);    // sigmoid(s)
            const float bce2 = -__log2f(q + EPSF);              // bce / ln2
            const uint32_t key = ok ? f2key(bce2) : 0u;
            kk[k][j] = key;
            if (ok) atomicAdd(&S.hist[(key >> 24) * 17 + ((key >> 20) & 15)], 1u);
        }
    }
    __syncthreads();

    // ---- Select 1: top 12 key bits
    select4096(S, tid);
    const uint32_t pref1 = (uint32_t)S.bin;

    // ---- Pass 2: middle 12 bits among prefix-matching keys (register scan)
    #pragma unroll
    for (int k = 0; k < 17; ++k) S.hist[tid + k * TPB] = 0;
    __syncthreads();
    #pragma unroll
    for (int k = 0; k < NK; ++k) {
        #pragma unroll
        for (int j = 0; j < 4; ++j) {
            const uint32_t key = kk[k][j];
            if ((key >> 20) == pref1)
                atomicAdd(&S.hist[((key >> 12) & 0xFFu) * 17 + ((key >> 8) & 15)], 1u);
        }
    }
    __syncthreads();
    select4096(S, tid);
    const uint32_t pref2 = (pref1 << 12) | (uint32_t)S.bin;

    // ---- Pass 3: low 8 bits
    for (int i = tid; i < SEGW; i += TPB) S.hist[i] = 0;
    __syncthreads();
    #pragma unroll
    for (int k = 0; k < NK; ++k) {
        #pragma unroll
        for (int j = 0; j < 4; ++j) {
            const uint32_t key = kk[k][j];
            if ((key >> 8) == pref2)
                atomicAdd(&S.hist[((key >> 4) & 15) * 17 + (key & 15)], 1u);
        }
    }
    __syncthreads();
    select256(S, tid);
    const uint32_t K = (pref2 << 8) | (uint32_t)S.bin;

    // ---- Final: sum keys strictly greater than K (register scan) + ties.
    float sum = 0.0f;
    uint32_t cnt = 0;
    #pragma unroll
    for (int k = 0; k < NK; ++k) {
        #pragma unroll
        for (int j = 0; j < 4; ++j) {
            const uint32_t key = kk[k][j];
            if (key > K) { sum += key2f(key); cnt++; }
        }
    }
    #pragma unroll
    for (int off = 32; off > 0; off >>= 1) {
        sum += __shfl_down(sum, off);
        cnt += __shfl_down(cnt, off);
    }
    const int wid = tid >> 6;
    if ((tid & 63) == 0) { S.wred[wid] = sum; S.wcnt[wid] = cnt; }
    __syncthreads();
    if (tid == 0) {
        const float s = S.wred[0] + S.wred[1] + S.wred[2] + S.wred[3];
        const int   c = (int)(S.wcnt[0] + S.wcnt[1] + S.wcnt[2] + S.wcnt[3]);
        const float tot = s + (float)(MTOP - c) * key2f(K);
        atomicAdd(out, tot * scale);
    }
}

extern "C" void kernel_launch(void* const* d_in, const int* in_sizes, int n_in,
                              void* d_out, int out_size, void* d_ws, size_t ws_size,
                              hipStream_t stream) {
    const float* logits  = (const float*)d_in[0];
    const float* targets = (const float*)d_in[1];
    float* out = (float*)d_out;

    const int Lr = 10000;
    const int B  = in_sizes[0] / Lr;
    // bce kept in log2 domain in-kernel; fold ln2 into the final scale
    const float scale = 0.69314718055994531f / ((float)MTOP * (float)B);

    hipMemsetAsync(out, 0, sizeof(float), stream);
    bce_topk_kernel<<<B, TPB, 0, stream>>>(logits, targets, out, Lr, scale);
}

// Round 6
// 331.002 us; speedup vs baseline: 1.3247x; 1.0427x over previous
//
#include <hip/hip_runtime.h>
#include <stdint.h>

#define TPB    1024
#define NK     3              // float4-batches per thread: 1024*3*4 = 12288 >= 10000
#define MTOP   50
#define HWORDS (256 * 17)     // 4096-bin hist, padded [256 groups][16+1]
#define SEGW   (16 * 17)      // padded 256 segment sums
#define LOG2E  1.4426950408889634f

struct Shared {
    uint32_t hist[HWORDS];
    uint32_t segsum[SEGW];
    int bin, rem;
    float    wred[16];
    uint32_t wcnt[16];
};

// Wave-parallel rank-pick over 16 values held by lanes 0..15 (lanes>=16 hold 0).
// Scanning from index 15 downward, find first idx where the running count
// reaches rem; update rem to the residual within that idx. Wave 0 only.
__device__ __forceinline__ int pick16(uint32_t v, int lane, int& rem) {
    uint32_t sfx = v;
    #pragma unroll
    for (int off = 1; off < 16; off <<= 1) {
        uint32_t t = __shfl_down(sfx, off);
        if (lane + off < 16) sfx += t;
    }
    bool p = (lane < 16) && ((int)sfx >= rem);
    unsigned long long m = __ballot(p);
    int idx = 63 - __builtin_clzll(m);
    uint32_t sfx_at = __shfl(sfx, idx);
    uint32_t v_at   = __shfl(v,   idx);
    rem -= (int)(sfx_at - v_at);
    return idx;
}

// Rank-select over the padded 4096-bin hist. In: S.rem. Out: S.bin, S.rem.
__device__ void select4096(Shared& S, int tid) {
    if (tid < 256) {
        uint32_t s = 0;
        #pragma unroll
        for (int j = 0; j < 16; ++j) s += S.hist[tid * 17 + j];   // stride-17: conflict-free
        S.segsum[(tid >> 4) * 17 + (tid & 15)] = s;
    }
    __syncthreads();
    if (tid < 64) {
        const int lane = tid;
        int rem = S.rem;
        uint32_t sup = 0;
        if (lane < 16) {
            #pragma unroll
            for (int j = 0; j < 16; ++j) sup += S.segsum[lane * 17 + j];
        }
        const int s1 = pick16(sup, lane, rem);
        const uint32_t seg = (lane < 16) ? S.segsum[s1 * 17 + lane] : 0;
        const int s2 = pick16(seg, lane, rem);
        const int g = (s1 << 4) + s2;
        const uint32_t h = (lane < 16) ? S.hist[g * 17 + lane] : 0;
        const int s3 = pick16(h, lane, rem);
        if (lane == 0) { S.bin = (g << 4) + s3; S.rem = rem; }
    }
    __syncthreads();
}

// Rank-select over 256 padded bins (groups 0..15).
__device__ void select256(Shared& S, int tid) {
    if (tid < 64) {
        const int lane = tid;
        int rem = S.rem;
        uint32_t sup = 0;
        if (lane < 16) {
            #pragma unroll
            for (int j = 0; j < 16; ++j) sup += S.hist[lane * 17 + j];
        }
        const int s1 = pick16(sup, lane, rem);
        const uint32_t h = (lane < 16) ? S.hist[s1 * 17 + lane] : 0;
        const int s2 = pick16(h, lane, rem);
        if (lane == 0) { S.bin = (s1 << 4) + s2; S.rem = rem; }
    }
    __syncthreads();
}

__global__ __launch_bounds__(TPB, 8)
void bce_topk_kernel(const float* __restrict__ logits,
                     const float* __restrict__ targets,
                     float* __restrict__ out,
                     int Lr, float scale)
{
    __shared__ Shared S;
    const int tid = threadIdx.x;
    const size_t rowbase = (size_t)blockIdx.x * (size_t)Lr;
    const float4* lg = (const float4*)(logits + rowbase);
    const float4* tg = (const float4*)(targets + rowbase);
    const int nv = Lr >> 2;   // 2500 float4s per row (Lr % 4 == 0)

    for (int i = tid; i < HWORDS; i += TPB) S.hist[i] = 0;
    if (tid == 0) S.rem = MTOP;
    __syncthreads();

    // ---- Pass A: issue ALL 6 loads up-front (deep pipeline), then compute.
    // bce kept in log2 domain: bce2 = log2(1 + 2^u), u = (t ? -x : x)*log2e.
    // bce2 > 0 always, so raw float bits ARE the monotonic sort key.
    const int i0 = tid, i1 = tid + TPB, i2 = tid + 2 * TPB;
    const int c0 = min(i0, nv - 1), c1 = min(i1, nv - 1), c2 = min(i2, nv - 1);
    const float4 l0 = lg[c0], l1 = lg[c1], l2 = lg[c2];
    const float4 t0 = tg[c0], t1 = tg[c1], t2 = tg[c2];

    uint32_t kk[NK][4];
    #define COMPUTE_BATCH(K, LV, TV, OK)                                        \
    {                                                                           \
        const float xv[4] = {LV.x, LV.y, LV.z, LV.w};                           \
        const float tv[4] = {TV.x, TV.y, TV.z, TV.w};                           \
        _Pragma("unroll")                                                       \
        for (int j = 0; j < 4; ++j) {                                           \
            const float u = xv[j] * (tv[j] != 0.0f ? -LOG2E : LOG2E);           \
            const float bce2 = __log2f(1.0f + __builtin_amdgcn_exp2f(u));       \
            const uint32_t key = (OK) ? __float_as_uint(bce2) : 0u;             \
            kk[K][j] = key;                                                     \
            if (OK) atomicAdd(&S.hist[(key >> 24) * 17 + ((key >> 20) & 15)], 1u); \
        }                                                                       \
    }
    COMPUTE_BATCH(0, l0, t0, (i0 < nv));
    COMPUTE_BATCH(1, l1, t1, (i1 < nv));
    COMPUTE_BATCH(2, l2, t2, (i2 < nv));
    #undef COMPUTE_BATCH
    __syncthreads();

    // ---- Select 1: top 12 key bits
    select4096(S, tid);
    const uint32_t pref1 = (uint32_t)S.bin;

    // ---- Pass 2: middle 12 bits among prefix-matching keys (register scan)
    for (int i = tid; i < HWORDS; i += TPB) S.hist[i] = 0;
    __syncthreads();
    #pragma unroll
    for (int k = 0; k < NK; ++k) {
        #pragma unroll
        for (int j = 0; j < 4; ++j) {
            const uint32_t key = kk[k][j];
            if ((key >> 20) == pref1)
                atomicAdd(&S.hist[((key >> 12) & 0xFFu) * 17 + ((key >> 8) & 15)], 1u);
        }
    }
    __syncthreads();
    select4096(S, tid);
    const uint32_t pref2 = (pref1 << 12) | (uint32_t)S.bin;

    // ---- Pass 3: low 8 bits
    for (int i = tid; i < SEGW; i += TPB) S.hist[i] = 0;
    __syncthreads();
    #pragma unroll
    for (int k = 0; k < NK; ++k) {
        #pragma unroll
        for (int j = 0; j < 4; ++j) {
            const uint32_t key = kk[k][j];
            if ((key >> 8) == pref2)
                atomicAdd(&S.hist[((key >> 4) & 15) * 17 + (key & 15)], 1u);
        }
    }
    __syncthreads();
    select256(S, tid);
    const uint32_t K = (pref2 << 8) | (uint32_t)S.bin;

    // ---- Final: sum keys strictly greater than K (register scan) + ties.
    float sum = 0.0f;
    uint32_t cnt = 0;
    #pragma unroll
    for (int k = 0; k < NK; ++k) {
        #pragma unroll
        for (int j = 0; j < 4; ++j) {
            const uint32_t key = kk[k][j];
            if (key > K) { sum += __uint_as_float(key); cnt++; }
        }
    }
    #pragma unroll
    for (int off = 32; off > 0; off >>= 1) {
        sum += __shfl_down(sum, off);
        cnt += __shfl_down(cnt, off);
    }
    const int wid = tid >> 6;
    if ((tid & 63) == 0) { S.wred[wid] = sum; S.wcnt[wid] = cnt; }
    __syncthreads();
    if (tid == 0) {
        float s = 0.0f; int c = 0;
        #pragma unroll
        for (int w = 0; w < TPB / 64; ++w) { s += S.wred[w]; c += (int)S.wcnt[w]; }
        const float tot = s + (float)(MTOP - c) * __uint_as_float(K);
        atomicAdd(out, tot * scale);
    }
}

extern "C" void kernel_launch(void* const* d_in, const int* in_sizes, int n_in,
                              void* d_out, int out_size, void* d_ws, size_t ws_size,
                              hipStream_t stream) {
    const float* logits  = (const float*)d_in[0];
    const float* targets = (const float*)d_in[1];
    float* out = (float*)d_out;

    const int Lr = 10000;
    const int B  = in_sizes[0] / Lr;
    // keys are bce/ln2; fold ln2 into the final scale
    const float scale = 0.69314718055994531f / ((float)MTOP * (float)B);

    hipMemsetAsync(out, 0, sizeof(float), stream);
    bce_topk_kernel<<<B, TPB, 0, stream>>>(logits, targets, out, Lr, scale);
}